// Round 1
// baseline (371.867 us; speedup 1.0000x reference)
//
#include <hip/hip_runtime.h>

// Problem constants (fixed by setup_inputs()).
#define BATCH 32
#define HGT   1024
#define WID   1024
#define KREG  4
#define HALF  20   // SIZE/2, SIZE=40

__device__ __forceinline__ float wave_reduce_sum(float v) {
    #pragma unroll
    for (int off = 32; off > 0; off >>= 1)
        v += __shfl_down(v, off, 64);
    return v;
}

// ---------------------------------------------------------------------------
// Kernel 1: global sums  ws[0]=sum(P*G), ws[1]=sum(P), ws[2]=sum(G)
// ---------------------------------------------------------------------------
__global__ __launch_bounds__(256) void global_sums_kernel(
        const float4* __restrict__ p, const float4* __restrict__ g,
        long n4, double* __restrict__ ws) {
    float sp = 0.f, sg = 0.f, spg = 0.f;
    long idx    = (long)blockIdx.x * blockDim.x + threadIdx.x;
    long stride = (long)gridDim.x * blockDim.x;
    for (long i = idx; i < n4; i += stride) {
        float4 a = p[i];
        float4 b = g[i];
        sp  += (a.x + a.y) + (a.z + a.w);
        sg  += (b.x + b.y) + (b.z + b.w);
        spg += (a.x * b.x + a.y * b.y) + (a.z * b.z + a.w * b.w);
    }
    sp  = wave_reduce_sum(sp);
    sg  = wave_reduce_sum(sg);
    spg = wave_reduce_sum(spg);

    __shared__ float smem[3][4];
    int lane = threadIdx.x & 63;
    int wv   = threadIdx.x >> 6;
    if (lane == 0) { smem[0][wv] = spg; smem[1][wv] = sp; smem[2][wv] = sg; }
    __syncthreads();
    if (threadIdx.x == 0) {
        float tpg = 0.f, tp = 0.f, tg = 0.f;
        int nw = blockDim.x >> 6;
        for (int w = 0; w < nw; ++w) { tpg += smem[0][w]; tp += smem[1][w]; tg += smem[2][w]; }
        atomicAdd(&ws[0], (double)tpg);
        atomicAdd(&ws[1], (double)tp);
        atomicAdd(&ws[2], (double)tg);
    }
}

// ---------------------------------------------------------------------------
// Kernel 2: per-region soft IoU, accumulated into ws[3].
// One block per (b, k) region; region is <= 40x40 pixels.
// ---------------------------------------------------------------------------
__device__ __forceinline__ void region_bounds(int c, int dim, int& s, int& e) {
    s = max(c - HALF, 0);
    e = min(c + HALF, dim);
    int n = e - s;
    bool odd_small = ((n & 1) != 0) && (n < 2 * HALF);
    if (odd_small && s == 0) e -= 1;   // matches: end = where(odd & start==0, end-1, end)
    if (odd_small && e == dim) s += 1; // matches: start = where(odd & end==dim, start+1, start)
}

__global__ __launch_bounds__(256) void region_iou_kernel(
        const float* __restrict__ p, const float* __restrict__ g,
        const int* __restrict__ cents, double* __restrict__ ws) {
    int r = blockIdx.x;            // 0 .. BATCH*KREG-1
    int b = r / KREG;
    int cy = cents[r * 2 + 0];
    int cx = cents[r * 2 + 1];

    int sy, ey, sx, ex;
    region_bounds(cy, HGT, sy, ey);
    region_bounds(cx, WID, sx, ex);
    int h = ey - sy;
    int w = ex - sx;
    int npix = h * w;

    const float* pb = p + (size_t)b * HGT * WID;
    const float* gb = g + (size_t)b * HGT * WID;

    float sp = 0.f, sg = 0.f, spg = 0.f;
    for (int i = threadIdx.x; i < npix; i += blockDim.x) {
        int yy = sy + i / w;
        int xx = sx + i % w;
        float pv = pb[(size_t)yy * WID + xx];
        float gv = gb[(size_t)yy * WID + xx];
        sp  += pv;
        sg  += gv;
        spg += pv * gv;
    }
    sp  = wave_reduce_sum(sp);
    sg  = wave_reduce_sum(sg);
    spg = wave_reduce_sum(spg);

    __shared__ float smem[3][4];
    int lane = threadIdx.x & 63;
    int wv   = threadIdx.x >> 6;
    if (lane == 0) { smem[0][wv] = spg; smem[1][wv] = sp; smem[2][wv] = sg; }
    __syncthreads();
    if (threadIdx.x == 0) {
        float tpg = 0.f, tp = 0.f, tg = 0.f;
        int nw = blockDim.x >> 6;
        for (int w2 = 0; w2 < nw; ++w2) { tpg += smem[0][w2]; tp += smem[1][w2]; tg += smem[2][w2]; }
        float iou = (tpg + 1.0f) / (tp + tg - tpg + 1.0f);
        atomicAdd(&ws[3], (double)iou);
    }
}

// ---------------------------------------------------------------------------
// Kernel 3: finalize scalar loss.
// ---------------------------------------------------------------------------
__global__ void finalize_kernel(const double* __restrict__ ws, float* __restrict__ out) {
    double inter = ws[0], sp = ws[1], sg = ws[2], siou = ws[3];
    double loss_global = 1.0 - (inter + 1.0) / (sp + sg - inter + 1.0);
    double loss_region = 1.0 - siou / (double)(BATCH * KREG);
    out[0] = (float)(loss_global + loss_region);
}

extern "C" void kernel_launch(void* const* d_in, const int* in_sizes, int n_in,
                              void* d_out, int out_size, void* d_ws, size_t ws_size,
                              hipStream_t stream) {
    const float* preds = (const float*)d_in[0];
    const float* gt    = (const float*)d_in[1];
    const int*   cents = (const int*)d_in[2];
    float*  out = (float*)d_out;
    double* ws  = (double*)d_ws;

    // Zero the 4 accumulator doubles (ws is poisoned with 0xAA each call).
    hipMemsetAsync(d_ws, 0, 4 * sizeof(double), stream);

    long n4 = (long)BATCH * HGT * WID / 4;
    global_sums_kernel<<<4096, 256, 0, stream>>>(
        (const float4*)preds, (const float4*)gt, n4, ws);
    region_iou_kernel<<<BATCH * KREG, 256, 0, stream>>>(preds, gt, cents, ws);
    finalize_kernel<<<1, 1, 0, stream>>>(ws, out);
}

// Round 2
// 293.281 us; speedup vs baseline: 1.2680x; 1.2680x over previous
//
#include <hip/hip_runtime.h>

// Problem constants (fixed by setup_inputs()).
#define BATCH 32
#define HGT   1024
#define WID   1024
#define KREG  4
#define HALF  20   // SIZE/2, SIZE=40

#define SUM_BLOCKS 4096
#define SUM_THREADS 256
#define UNROLL 8   // n4 = 32*1024*1024/4 = 8388608 = 4096*256*8 exactly

__device__ __forceinline__ float wave_reduce_f(float v) {
    #pragma unroll
    for (int off = 32; off > 0; off >>= 1)
        v += __shfl_down(v, off, 64);
    return v;
}

__device__ __forceinline__ double wave_reduce_d(double v) {
    #pragma unroll
    for (int off = 32; off > 0; off >>= 1)
        v += __shfl_down(v, off, 64);
    return v;
}

// ---------------------------------------------------------------------------
// Kernel 1: global partial sums (SoA): part[b], part[NB+b], part[2*NB+b]
//           = blockwise sum(P*G), sum(P), sum(G)
// Fully unrolled: 16 independent float4 loads in flight per thread.
// ---------------------------------------------------------------------------
__global__ __launch_bounds__(SUM_THREADS) void global_sums_kernel(
        const float4* __restrict__ p, const float4* __restrict__ g,
        float* __restrict__ part) {
    const long stride = (long)SUM_BLOCKS * SUM_THREADS;
    const long base   = (long)blockIdx.x * SUM_THREADS + threadIdx.x;

    float4 a[UNROLL], b[UNROLL];
    #pragma unroll
    for (int j = 0; j < UNROLL; ++j) a[j] = p[base + (long)j * stride];
    #pragma unroll
    for (int j = 0; j < UNROLL; ++j) b[j] = g[base + (long)j * stride];

    float sp = 0.f, sg = 0.f, spg = 0.f;
    #pragma unroll
    for (int j = 0; j < UNROLL; ++j) {
        sp  += (a[j].x + a[j].y) + (a[j].z + a[j].w);
        sg  += (b[j].x + b[j].y) + (b[j].z + b[j].w);
        spg += (a[j].x * b[j].x + a[j].y * b[j].y)
             + (a[j].z * b[j].z + a[j].w * b[j].w);
    }

    spg = wave_reduce_f(spg);
    sp  = wave_reduce_f(sp);
    sg  = wave_reduce_f(sg);

    __shared__ float smem[3][4];
    int lane = threadIdx.x & 63;
    int wv   = threadIdx.x >> 6;
    if (lane == 0) { smem[0][wv] = spg; smem[1][wv] = sp; smem[2][wv] = sg; }
    __syncthreads();
    if (threadIdx.x == 0) {
        float tpg = 0.f, tp = 0.f, tg = 0.f;
        #pragma unroll
        for (int w = 0; w < SUM_THREADS / 64; ++w) {
            tpg += smem[0][w]; tp += smem[1][w]; tg += smem[2][w];
        }
        part[blockIdx.x]                  = tpg;
        part[SUM_BLOCKS + blockIdx.x]     = tp;
        part[2 * SUM_BLOCKS + blockIdx.x] = tg;
    }
}

// ---------------------------------------------------------------------------
// Kernel 2: per-region soft IoU -> ious[r], one block per (b,k) region.
// ---------------------------------------------------------------------------
__device__ __forceinline__ void region_bounds(int c, int dim, int& s, int& e) {
    s = max(c - HALF, 0);
    e = min(c + HALF, dim);
    int n = e - s;
    bool odd_small = ((n & 1) != 0) && (n < 2 * HALF);
    if (odd_small && s == 0) e -= 1;
    if (odd_small && e == dim) s += 1;
}

__global__ __launch_bounds__(256) void region_iou_kernel(
        const float* __restrict__ p, const float* __restrict__ g,
        const int* __restrict__ cents, float* __restrict__ ious) {
    int r = blockIdx.x;            // 0 .. BATCH*KREG-1
    int b = r / KREG;
    int cy = cents[r * 2 + 0];
    int cx = cents[r * 2 + 1];

    int sy, ey, sx, ex;
    region_bounds(cy, HGT, sy, ey);
    region_bounds(cx, WID, sx, ex);
    int h = ey - sy;
    int w = ex - sx;
    int npix = h * w;

    const float* pb = p + (size_t)b * HGT * WID;
    const float* gb = g + (size_t)b * HGT * WID;

    float sp = 0.f, sg = 0.f, spg = 0.f;
    for (int i = threadIdx.x; i < npix; i += blockDim.x) {
        int yy = sy + i / w;
        int xx = sx + i % w;
        float pv = pb[(size_t)yy * WID + xx];
        float gv = gb[(size_t)yy * WID + xx];
        sp  += pv;
        sg  += gv;
        spg += pv * gv;
    }
    spg = wave_reduce_f(spg);
    sp  = wave_reduce_f(sp);
    sg  = wave_reduce_f(sg);

    __shared__ float smem[3][4];
    int lane = threadIdx.x & 63;
    int wv   = threadIdx.x >> 6;
    if (lane == 0) { smem[0][wv] = spg; smem[1][wv] = sp; smem[2][wv] = sg; }
    __syncthreads();
    if (threadIdx.x == 0) {
        float tpg = 0.f, tp = 0.f, tg = 0.f;
        #pragma unroll
        for (int w2 = 0; w2 < 4; ++w2) {
            tpg += smem[0][w2]; tp += smem[1][w2]; tg += smem[2][w2];
        }
        ious[r] = (tpg + 1.0f) / (tp + tg - tpg + 1.0f);
    }
}

// ---------------------------------------------------------------------------
// Kernel 3: finalize — reduce partials (double) and compute scalar loss.
// ---------------------------------------------------------------------------
__global__ __launch_bounds__(256) void finalize_kernel(
        const float* __restrict__ part, const float* __restrict__ ious,
        float* __restrict__ out) {
    double spg = 0.0, sp = 0.0, sg = 0.0, siou = 0.0;
    for (int i = threadIdx.x; i < SUM_BLOCKS; i += 256) {
        spg += (double)part[i];
        sp  += (double)part[SUM_BLOCKS + i];
        sg  += (double)part[2 * SUM_BLOCKS + i];
    }
    if (threadIdx.x < BATCH * KREG) siou = (double)ious[threadIdx.x];

    spg  = wave_reduce_d(spg);
    sp   = wave_reduce_d(sp);
    sg   = wave_reduce_d(sg);
    siou = wave_reduce_d(siou);

    __shared__ double smem[4][4];
    int lane = threadIdx.x & 63;
    int wv   = threadIdx.x >> 6;
    if (lane == 0) {
        smem[0][wv] = spg; smem[1][wv] = sp; smem[2][wv] = sg; smem[3][wv] = siou;
    }
    __syncthreads();
    if (threadIdx.x == 0) {
        double tpg = 0.0, tp = 0.0, tg = 0.0, ti = 0.0;
        #pragma unroll
        for (int w = 0; w < 4; ++w) {
            tpg += smem[0][w]; tp += smem[1][w]; tg += smem[2][w]; ti += smem[3][w];
        }
        double loss_global = 1.0 - (tpg + 1.0) / (tp + tg - tpg + 1.0);
        double loss_region = 1.0 - ti / (double)(BATCH * KREG);
        out[0] = (float)(loss_global + loss_region);
    }
}

extern "C" void kernel_launch(void* const* d_in, const int* in_sizes, int n_in,
                              void* d_out, int out_size, void* d_ws, size_t ws_size,
                              hipStream_t stream) {
    const float* preds = (const float*)d_in[0];
    const float* gt    = (const float*)d_in[1];
    const int*   cents = (const int*)d_in[2];
    float* out = (float*)d_out;

    float* part = (float*)d_ws;                       // 3*SUM_BLOCKS floats
    float* ious = part + 3 * SUM_BLOCKS;              // BATCH*KREG floats

    global_sums_kernel<<<SUM_BLOCKS, SUM_THREADS, 0, stream>>>(
        (const float4*)preds, (const float4*)gt, part);
    region_iou_kernel<<<BATCH * KREG, 256, 0, stream>>>(preds, gt, cents, ious);
    finalize_kernel<<<1, 256, 0, stream>>>(part, ious, out);
}